// Round 6
// baseline (39.771 us; speedup 1.0000x reference)
//
#include <hip/hip_runtime.h>
#include <math.h>

// Problem constants (from setup_inputs)
#define BB 8
#define HW 4096
#define LTXT 8192
#define GG 4096
#define DD 256

// Worker grid: 1216 blocks x 64 threads (1 wave/block, no LDS, no barriers)
//   [0,256)     vision chains:  b = id/32,  chunk = id%32   (128 rows/chunk, 2 rows/thread)
//   [256,768)   text chains:    b = (id-256)/64, chunk = %64
//   [768,1024)  genomic chains: b = (id-768)/32, chunk = %32
//   [1024,1088) vision audit (64 blocks, thread = row)
//   [1088,1216) text audit (128 blocks, thread = position)
//
// ws floats: [0,1024) vision chunk products, [1024,3072) text, [3072,4096) genomic
//    doubles @byte 65536: [0,64) vision-audit partials, [64,192) text-audit partials

struct QF { float w, x, y, z; };

__device__ __forceinline__ QF qmulf(const QF a, const QF b) {
    QF r;
    r.w = fmaf(a.w, b.w, -fmaf(a.x, b.x, fmaf(a.y, b.y, a.z * b.z)));
    r.x = fmaf(a.w, b.x, fmaf(a.x, b.w, fmaf(a.y, b.z, -(a.z * b.y))));
    r.y = fmaf(a.w, b.y, fmaf(a.y, b.w, fmaf(a.z, b.x, -(a.x * b.z))));
    r.z = fmaf(a.w, b.z, fmaf(a.x, b.y, fmaf(a.z, b.w, -(a.y * b.x))));
    return r;
}

// Ordered (non-commutative) 64-lane butterfly: lower lane's product on the left.
__device__ __forceinline__ QF wave_ordered_prod(QF p, int lane) {
    #pragma unroll
    for (int s = 1; s < 64; s <<= 1) {
        QF o;
        o.w = __shfl_xor(p.w, s, 64);
        o.x = __shfl_xor(p.x, s, 64);
        o.y = __shfl_xor(p.y, s, 64);
        o.z = __shfl_xor(p.z, s, 64);
        const bool hi = (lane & s) != 0;
        QF a = hi ? o : p;
        QF b = hi ? p : o;
        p = qmulf(a, b);
    }
    return p;
}

// Thread = TWO consecutive rows (weight loads amortized 2x, 2-way chain ILP).
// Double-buffered register staging of weight batches; deferred normalization
// (raw product + s = prod(n_f32 + 1e-8f), one precise divide per batch per row).
template<int K, int BQ>
__device__ __forceinline__ void chain_block64(
    const float* __restrict__ X, const float* __restrict__ W,
    const float* __restrict__ bias, int rowBase, float* __restrict__ out4)
{
    constexpr int V = K + 1;          // float4 vectors per quat (bias + K weight rows)
    constexpr int NB = 64 / BQ;       // batches per row-pass
    const int t = threadIdx.x;        // 0..63
    const int r0 = rowBase + 2 * t;

    float xa[K], xb[K];
    #pragma unroll
    for (int k = 0; k < K; ++k) {
        xa[k] = X[(size_t)r0 * K + k];
        xb[k] = X[(size_t)(r0 + 1) * K + k];
    }

    float4 A[BQ * V], Bv[BQ * V];
    QF pa = {1.0f, 0.0f, 0.0f, 0.0f}, pb = {1.0f, 0.0f, 0.0f, 0.0f};

    auto LOADB = [&](float4* dst, int bidx) {
        const float* bb = bias + 4 * (bidx * BQ);
        const float* wb = W + 4 * (bidx * BQ);
        #pragma unroll
        for (int j = 0; j < BQ; ++j) {
            dst[j * V] = *(const float4*)(bb + 4 * j);
            #pragma unroll
            for (int k = 0; k < K; ++k)
                dst[j * V + 1 + k] = *(const float4*)(wb + k * DD + 4 * j);
        }
    };

    auto COMPUTE = [&](const float4* src, int bidx) {
        QF ga, gb; float sa, sb;
        #pragma unroll
        for (int j = 0; j < BQ; ++j) {
            const float4 b4 = src[j * V];
            float a0 = b4.x, a1 = b4.y, a2 = b4.z, a3 = b4.w;
            float c0 = b4.x, c1 = b4.y, c2 = b4.z, c3 = b4.w;
            #pragma unroll
            for (int k = 0; k < K; ++k) {
                const float4 w4 = src[j * V + 1 + k];
                a0 = fmaf(xa[k], w4.x, a0);
                a1 = fmaf(xa[k], w4.y, a1);
                a2 = fmaf(xa[k], w4.z, a2);
                a3 = fmaf(xa[k], w4.w, a3);
                c0 = fmaf(xb[k], w4.x, c0);
                c1 = fmaf(xb[k], w4.y, c1);
                c2 = fmaf(xb[k], w4.z, c2);
                c3 = fmaf(xb[k], w4.w, c3);
            }
            const float na = sqrtf(fmaf(a0, a0, fmaf(a1, a1, fmaf(a2, a2, a3 * a3))));
            const float nb = sqrtf(fmaf(c0, c0, fmaf(c1, c1, fmaf(c2, c2, c3 * c3))));
            QF qa = { a0, a1, a2, a3 };
            QF qb = { c0, c1, c2, c3 };
            if (j == 0) { ga = qa; sa = na + 1e-8f; gb = qb; sb = nb + 1e-8f; }
            else {
                ga = qmulf(ga, qa); sa *= (na + 1e-8f);
                gb = qmulf(gb, qb); sb *= (nb + 1e-8f);
            }
        }
        const float ia = 1.0f / sa, ib = 1.0f / sb;   // one precise divide per batch per row
        QF gan = { ga.w * ia, ga.x * ia, ga.y * ia, ga.z * ia };
        QF gbn = { gb.w * ib, gb.x * ib, gb.y * ib, gb.z * ib };
        if (bidx == 0) { pa = gan; pb = gbn; }        // wave-uniform branch
        else           { pa = qmulf(pa, gan); pb = qmulf(pb, gbn); }
    };

    LOADB(A, 0);
    for (int gg = 0; gg < NB / 2; ++gg) {
        LOADB(Bv, 2 * gg + 1);                        // prefetch odd batch
        COMPUTE(A, 2 * gg);
        const int nb2 = (2 * gg + 2 < NB) ? (2 * gg + 2) : (NB - 1);
        LOADB(A, nb2);                                // prefetch next even batch
        COMPUTE(Bv, 2 * gg + 1);
    }

    QF p = qmulf(pa, pb);                             // rows 2t, 2t+1 in order
    p = wave_ordered_prod(p, t);
    if (t == 0) {
        float4 o = { p.w, p.x, p.y, p.z };
        *(float4*)out4 = o;
    }
}

__global__ __launch_bounds__(64) void worker_kernel(
    const float* __restrict__ vis, const float* __restrict__ txt, const float* __restrict__ gen,
    const float* __restrict__ Wv, const float* __restrict__ bv,
    const float* __restrict__ Wt, const float* __restrict__ bt,
    const float* __restrict__ Wg, const float* __restrict__ bg,
    float* __restrict__ wsf, double* __restrict__ dws)
{
    const int t  = threadIdx.x;
    const int id = blockIdx.x;

    if (id < 256) {
        const int b = id >> 5, chunk = id & 31;
        chain_block64<3, 4>(vis + (size_t)b * HW * 3, Wv, bv, chunk * 128,
                            wsf + (size_t)id * 4);
    } else if (id < 768) {
        const int i2 = id - 256;
        const int b = i2 >> 6, chunk = i2 & 63;
        chain_block64<1, 8>(txt + (size_t)b * LTXT, Wt, bt, chunk * 128,
                            wsf + 1024 + (size_t)i2 * 4);
    } else if (id < 1024) {
        const int i2 = id - 768;
        const int b = i2 >> 5, chunk = i2 & 31;
        chain_block64<4, 2>(gen + (size_t)b * GG * 4, Wg, bg, chunk * 128,
                            wsf + 3072 + (size_t)i2 * 4);
    } else if (id < 1088) {
        // ---------------- vision audit: thread = row ----------------
        const int aid = id - 1024;
        const int r = aid * 64 + t;           // 0..4095
        float gx[8], gy[8], gz[8];
        {
            float vx[8], vy[8], vz[8];
            #pragma unroll
            for (int b = 0; b < 8; ++b) {
                const size_t base = ((size_t)b * HW + r) * 3;
                vx[b] = vis[base]; vy[b] = vis[base+1]; vz[b] = vis[base+2];
            }
            #pragma unroll
            for (int b = 0; b < 8; ++b) {
                if (b == 0)      { gx[b] = vx[1]-vx[0];  gy[b] = vy[1]-vy[0];  gz[b] = vz[1]-vz[0]; }
                else if (b == 7) { gx[b] = vx[7]-vx[6];  gy[b] = vy[7]-vy[6];  gz[b] = vz[7]-vz[6]; }
                else             { gx[b] = (vx[b+1]-vx[b-1])*0.5f; gy[b] = (vy[b+1]-vy[b-1])*0.5f; gz[b] = (vz[b+1]-vz[b-1])*0.5f; }
            }
        }
        double acc = 0.0;
        #pragma unroll 4
        for (int i = 0; i < 64; ++i) {
            const float4 a0 = *(const float4*)(Wv + 4*i);
            const float4 a1 = *(const float4*)(Wv + DD + 4*i);
            const float4 a2 = *(const float4*)(Wv + 2*DD + 4*i);
            const float wq0 = a0.x + a0.y + a0.z + a0.w;
            const float wq1 = a1.x + a1.y + a1.z + a1.w;
            const float wq2 = a2.x + a2.y + a2.z + a2.w;
            float acc8 = 0.0f;
            #pragma unroll
            for (int b = 0; b < 8; ++b)
                acc8 += fabsf(fmaf(gx[b], wq0, fmaf(gy[b], wq1, gz[b] * wq2)));
            acc += (double)acc8;
        }
        #pragma unroll
        for (int s = 32; s > 0; s >>= 1) acc += __shfl_down(acc, s, 64);
        if (t == 0) dws[aid] = acc;
    } else {
        // ---------------- text audit (gradient factor) ----------------
        const int aid = id - 1088;
        const int l = aid * 64 + t;           // 0..8191
        float tv[8];
        #pragma unroll
        for (int b = 0; b < 8; ++b) tv[b] = txt[(size_t)b * LTXT + l];
        double acc = 0.0;
        #pragma unroll
        for (int b = 0; b < 8; ++b) {
            float gb;
            if (b == 0)      gb = tv[1] - tv[0];
            else if (b == 7) gb = tv[7] - tv[6];
            else             gb = (tv[b+1] - tv[b-1]) * 0.5f;
            acc += (double)fabsf(gb);
        }
        #pragma unroll
        for (int s = 32; s > 0; s >>= 1) acc += __shfl_down(acc, s, 64);
        if (t == 0) dws[64 + aid] = acc;
    }
}

__global__ __launch_bounds__(256) void finalize_kernel(
    const float* __restrict__ vis, const float* __restrict__ txt, const float* __restrict__ gen,
    const float* __restrict__ Wv, const float* __restrict__ bv,
    const float* __restrict__ Wt, const float* __restrict__ bt,
    const float* __restrict__ Wg, const float* __restrict__ bg,
    const float* __restrict__ wsf, const double* __restrict__ dws,
    float* __restrict__ out)
{
    __shared__ double sphi[24];     // phi[m][b]
    __shared__ double sred[256];
    __shared__ double s_sumv, s_sumt, s_sumw;
    const int t = threadIdx.x;
    const int lane = t & 63, w = t >> 6;

    // each wave handles 6 (m,b) pairs; lane-per-chunk ordered butterfly combine
    #pragma unroll
    for (int j = 0; j < 6; ++j) {
        const int pair = w * 6 + j;          // 0..23
        const int m = pair >> 3, b = pair & 7;
        const int nch = (m == 1) ? 64 : 32;
        const float* base = wsf + ((m == 0) ? 0 : (m == 1) ? 1024 : 3072) + (size_t)b * nch * 4;
        QF p = { 1.0f, 0.0f, 0.0f, 0.0f };
        if (lane < nch) {
            const float4 c0 = *(const float4*)(base + lane * 4);
            p = { c0.x, c0.y, c0.z, c0.w };
        }
        p = wave_ordered_prod(p, lane);
        if (lane == 0) {
            float lat[4];
            if (m == 0) {
                const float x0 = vis[(size_t)b*HW*3], x1 = vis[(size_t)b*HW*3+1], x2 = vis[(size_t)b*HW*3+2];
                #pragma unroll
                for (int c = 0; c < 4; ++c)
                    lat[c] = fmaf(x0, Wv[c], fmaf(x1, Wv[DD+c], fmaf(x2, Wv[2*DD+c], bv[c])));
            } else if (m == 1) {
                const float x0 = txt[(size_t)b*LTXT];
                #pragma unroll
                for (int c = 0; c < 4; ++c) lat[c] = fmaf(x0, Wt[c], bt[c]);
            } else {
                const float x0 = gen[(size_t)b*GG*4], x1 = gen[(size_t)b*GG*4+1],
                            x2 = gen[(size_t)b*GG*4+2], x3 = gen[(size_t)b*GG*4+3];
                #pragma unroll
                for (int c = 0; c < 4; ++c)
                    lat[c] = fmaf(x0, Wg[c], fmaf(x1, Wg[DD+c], fmaf(x2, Wg[2*DD+c], fmaf(x3, Wg[3*DD+c], bg[c]))));
            }
            const float n = sqrtf(fmaf(lat[0], lat[0], fmaf(lat[1], lat[1], fmaf(lat[2], lat[2], lat[3] * lat[3]))));
            const float inv = 1.0f / (n + 1e-8f);
            QF q0 = { lat[0]*inv, lat[1]*inv, lat[2]*inv, lat[3]*inv };
            p = qmulf(p, q0);
            double ww = (double)p.w;
            if (ww > 1.0) ww = 1.0;
            if (ww < -1.0) ww = -1.0;
            sphi[pair] = 2.0 * acos(ww);
        }
    }
    __syncthreads();

    // vision audit sum (64 partials)
    sred[t] = (t < 64) ? dws[t] : 0.0; __syncthreads();
    for (int off = 128; off > 0; off >>= 1) { if (t < off) sred[t] += sred[t+off]; __syncthreads(); }
    if (t == 0) s_sumv = sred[0];
    __syncthreads();

    // text audit sum (128 partials)
    sred[t] = (t < 128) ? dws[64 + t] : 0.0; __syncthreads();
    for (int off = 128; off > 0; off >>= 1) { if (t < off) sred[t] += sred[t+off]; __syncthreads(); }
    if (t == 0) s_sumt = sred[0];
    __syncthreads();

    // sum_i |wtq_i|
    double aw = 0.0;
    if (t < 64) {
        const int d0 = 4 * t;
        aw = (double)fabsf(Wt[d0] + Wt[d0+1] + Wt[d0+2] + Wt[d0+3]);
    }
    sred[t] = aw; __syncthreads();
    for (int off = 128; off > 0; off >>= 1) { if (t < off) sred[t] += sred[t+off]; __syncthreads(); }
    if (t == 0) s_sumw = sred[0];
    __syncthreads();

    if (t == 0) {
        double mv = 0.0, mt = 0.0;
        for (int b = 0; b < 8; ++b) { mv += sphi[b]; mt += sphi[8 + b]; }
        mv /= 8.0; mt /= 8.0;
        const double interf = fabs(mv - mt);
        for (int b = 0; b < 8; ++b)
            out[b] = (float)exp(-fabs(sphi[16 + b] - interf));
        out[8]  = (float)interf;
        out[9]  = (float)(s_sumv / 2097152.0);            // 8 * 4096 * 64
        out[10] = (float)(s_sumt * s_sumw / 4194304.0);   // 8 * 8192 * 64
    }
}

extern "C" void kernel_launch(void* const* d_in, const int* in_sizes, int n_in,
                              void* d_out, int out_size, void* d_ws, size_t ws_size,
                              hipStream_t stream) {
    (void)in_sizes; (void)n_in; (void)out_size; (void)ws_size;
    const float* vis = (const float*)d_in[0];
    const float* txt = (const float*)d_in[1];
    const float* gen = (const float*)d_in[2];
    const float* Wv  = (const float*)d_in[3];
    const float* bv  = (const float*)d_in[4];
    const float* Wt  = (const float*)d_in[5];
    const float* bt  = (const float*)d_in[6];
    const float* Wg  = (const float*)d_in[7];
    const float* bg  = (const float*)d_in[8];
    float*  wsf = (float*)d_ws;
    double* dws = (double*)((char*)d_ws + 65536);
    float*  out = (float*)d_out;

    hipLaunchKernelGGL(worker_kernel, dim3(1216), dim3(64), 0, stream,
                       vis, txt, gen, Wv, bv, Wt, bt, Wg, bg, wsf, dws);
    hipLaunchKernelGGL(finalize_kernel, dim3(1), dim3(256), 0, stream,
                       vis, txt, gen, Wv, bv, Wt, bt, Wg, bg, wsf, dws, out);
}